// Round 15
// baseline (222.738 us; speedup 1.0000x reference)
//
#include <hip/hip_runtime.h>
#include <math.h>

#define NCLI 100
#define CPAD 112                  // clients padded to 7*16
#define DK   64                   // d-rows per chunk
#define BFB  (CPAD * DK * 2)      // 14336 B bf16 transposed buffer
#define GBLK 1024                 // up to 4 blocks/CU

typedef short bf16x8 __attribute__((ext_vector_type(8)));  // 8 bf16 (4 VGPRs)
typedef float f32x4  __attribute__((ext_vector_type(4)));

// bf16 buffer byte offset for (client c, k-offset t). Row stride 128B = 8 x 16B
// slots; slot = (c&7) ^ ((c>>3)&7)  (r9/r10/r14-verified: fragment reads ~free,
// staging writes spread across 16 banks).
__device__ __forceinline__ int bf_byte(int c, int t) {
    int s = (c & 7) ^ ((c >> 3) & 7);
    return c * 128 + ((t * 2) ^ (s << 4));
}

// fp32 -> bf16 (RNE), bit pattern as ushort
__device__ __forceinline__ unsigned short f2bf(float x) {
    unsigned u = __float_as_uint(x);
    unsigned r = (u + 0x7fffu + ((u >> 16) & 1u)) >> 16;
    return (unsigned short)r;
}

// ---------------- tiny zero kernel (graph-safe G clear) ----------------
__global__ void zero_kernel(float4* __restrict__ p, int n4) {
    int i = blockIdx.x * blockDim.x + threadIdx.x;
    if (i < n4) p[i] = make_float4(0.f, 0.f, 0.f, 0.f);
}

// ---- issue-early: plain vectorized loads -> registers (proven ~7 TB/s path) ----
// 400 units (4 d-rows x 4 clients): s=0 all 256 threads, s=1 only tid<144.
// 25-lane runs are contiguous 400B segments -> well coalesced.
__device__ __forceinline__ void load_units(const float* __restrict__ A, long d0,
                                           long dtot, int tid, float4 pv[2][4]) {
#pragma unroll
    for (int s = 0; s < 2; ++s) {
        if (s == 0 || tid < 144) {
            const int u = tid + s * 256;
            const int rg = u / 25;           // 4-row group 0..15
            const int cg = u - rg * 25;      // 4-col group 0..24
#pragma unroll
            for (int r = 0; r < 4; ++r) {
                const long dr = d0 + rg * 4 + r;
                pv[s][r] = (dr < dtot) ? *(const float4*)(A + dr * NCLI + cg * 4)
                                       : make_float4(0.f, 0.f, 0.f, 0.f);
            }
        }
    }
}

// ---- write-late: convert pv -> bf16, transposed into swizzled bf tile ----
__device__ __forceinline__ void write_units(char* bf, int tid, const float4 pv[2][4]) {
#pragma unroll
    for (int s = 0; s < 2; ++s) {
        if (s == 0 || tid < 144) {
            const int u = tid + s * 256;
            const int rg = u / 25;
            const int cg = u - rg * 25;
#pragma unroll
            for (int j = 0; j < 4; ++j) {
                const int c = cg * 4 + j;
                ushort4 p;
                p.x = f2bf(((const float*)&pv[s][0])[j]);
                p.y = f2bf(((const float*)&pv[s][1])[j]);
                p.z = f2bf(((const float*)&pv[s][2])[j]);
                p.w = f2bf(((const float*)&pv[s][3])[j]);
                *(ushort4*)(bf + bf_byte(c, rg * 4)) = p;   // 8B, 8B-aligned
            }
        }
    }
}

// Wave W owns 16x16 output tiles: row a=W, b=W..6 (7-W tiles) and, for W>0,
// row a=7-W, b=7-W..6 (W tiles). Exactly 7 tiles per wave, A-frags {W, 7-W}.
template <int W>
__device__ __forceinline__ void compute_chunk(const char* bf, f32x4 acc[7]) {
    const int lane = threadIdx.x & 63;
    const int lrow = lane & 15;        // row/col within tile
    const int kgrp = lane >> 4;        // k-group 0..3 (8 bf16 each)
    constexpr int NB = 7 - W;          // b = W..6
#pragma unroll
    for (int kk = 0; kk < DK; kk += 32) {
        const int kb = kk + kgrp * 8;
        bf16x8 bfr[NB];
#pragma unroll
        for (int j = 0; j < NB; ++j)
            bfr[j] = *(const bf16x8*)(bf + bf_byte((W + j) * 16 + lrow, kb));
        bf16x8 a0 = *(const bf16x8*)(bf + bf_byte(W * 16 + lrow, kb));
#pragma unroll
        for (int j = 0; j < NB; ++j)
            acc[j] = __builtin_amdgcn_mfma_f32_16x16x32_bf16(a0, bfr[j], acc[j], 0, 0, 0);
        if constexpr (W > 0) {
            bf16x8 a1 = *(const bf16x8*)(bf + bf_byte((7 - W) * 16 + lrow, kb));
#pragma unroll
            for (int j = 0; j < W; ++j)
                acc[NB + j] = __builtin_amdgcn_mfma_f32_16x16x32_bf16(
                    a1, bfr[NB - W + j], acc[NB + j], 0, 0, 0);
        }
    }
}

template <int W>
__device__ __forceinline__ void store_acc(float* __restrict__ G, const f32x4 acc[7]) {
    const int lane = threadIdx.x & 63;
    const int cn = lane & 15;                 // output col within tile
    const int r0 = (lane >> 4) * 4;           // output row base within tile
#pragma unroll
    for (int j = 0; j < 7 - W; ++j) {         // tiles (W, W+j)
#pragma unroll
        for (int r = 0; r < 4; ++r) {
            int i = W * 16 + r0 + r;
            int k = (W + j) * 16 + cn;
            if (i < NCLI && k < NCLI) atomicAdd(&G[i * NCLI + k], acc[j][r]);
        }
    }
    if constexpr (W > 0) {
#pragma unroll
        for (int j = 0; j < W; ++j) {         // tiles (7-W, 7-W+j)
#pragma unroll
            for (int r = 0; r < 4; ++r) {
                int i = (7 - W) * 16 + r0 + r;
                int k = (7 - W + j) * 16 + cn;
                if (i < NCLI && k < NCLI) atomicAdd(&G[i * NCLI + k], acc[7 - W + j][r]);
            }
        }
    }
}

// ---------------- MFMA Gram: reg-staged pipeline (r5 schedule, spill fixed) ----------------
// A/B vs r14: staging via plain global_load_dwordx4 -> registers -> bf16 LDS
// (deletes raw buffers + LDS->LDS transpose; tests the gload_lds-BW-cap
// hypothesis). r5's schedule PASSED correctness; it failed on VGPR spill at
// __launch_bounds__(256,4) (cap 128). Here (256,3) -> cap ~170; est use ~130.
// Per iter e: { write_units pv->bf[e&1] (compiler vmcnt-waits on pv) |
// load_units pv <- chunk e+1 (in flight across barrier, in REGISTERS) |
// lgkmcnt(0) + raw s_barrier (NO vmcnt drain) | compute bf[e&1] }.
// Races: write(e+2)->bf[e&1] vs compute(e) reads: separated by barrier(e+1).
__global__ __launch_bounds__(256, 3) void gram_mfma(const float* __restrict__ A,
                                                    float* __restrict__ G,
                                                    long dtot, int nchunks) {
    __shared__ uint4 ldsq[2 * BFB / 16];   // 28672 B
    char* bf = (char*)ldsq;
    const int tid = threadIdx.x;
    const int wid = tid >> 6;

    // zero pad-client rows 100..111 in BOTH bf buffers (whole rows zero)
    for (int u = tid; u < 2 * (CPAD - NCLI) * 32; u += 256) {
        int b = u / ((CPAD - NCLI) * 32);
        int o = u - b * ((CPAD - NCLI) * 32);
        ((unsigned*)(bf + b * BFB + NCLI * 128))[o] = 0u;
    }
    __syncthreads();

    f32x4 acc[7];
#pragma unroll
    for (int q = 0; q < 7; ++q) acc[q] = (f32x4)(0.0f);

    int nb = 0;
    if ((int)blockIdx.x < nchunks)
        nb = (nchunks - 1 - (int)blockIdx.x) / (int)gridDim.x + 1;

    float4 pv[2][4];
    if (nb > 0)
        load_units(A, (long)blockIdx.x * DK, dtot, tid, pv);   // prologue

    for (int e = 0; e < nb; ++e) {
        char* bfc = bf + (e & 1) * BFB;
        write_units(bfc, tid, pv);                 // waits vmcnt on pv use
        if (e + 1 < nb)
            load_units(A, ((long)blockIdx.x + (long)(e + 1) * gridDim.x) * DK,
                       dtot, tid, pv);             // issue-early, fly over barrier
        asm volatile("s_waitcnt lgkmcnt(0)" ::: "memory");  // ds_writes visible
        __builtin_amdgcn_s_barrier();                       // no vmcnt drain
        asm volatile("" ::: "memory");

        if (wid == 0)      compute_chunk<0>(bfc, acc);
        else if (wid == 1) compute_chunk<1>(bfc, acc);
        else if (wid == 2) compute_chunk<2>(bfc, acc);
        else               compute_chunk<3>(bfc, acc);
    }

    if (wid == 0)      store_acc<0>(G, acc);
    else if (wid == 1) store_acc<1>(G, acc);
    else if (wid == 2) store_acc<2>(G, acc);
    else               store_acc<3>(G, acc);
}

// ---------------- Weights kernel: full FoolsGold weight computation, single block ----------------
__global__ __launch_bounds__(128) void weights_kernel(const float* __restrict__ G,
                                                      float* __restrict__ w) {
    __shared__ float cs[NCLI][NCLI + 1];
    __shared__ float nrm[NCLI], maxcs[NCLI], wv[NCLI];
    __shared__ float red[2];
    const int t = threadIdx.x;

    if (t < NCLI) {
        float g = G[t * NCLI + t];
        nrm[t] = fmaxf(sqrtf(g), 1e-12f);
    }
    __syncthreads();

    for (int idx = t; idx < NCLI * NCLI; idx += 128) {
        int i = idx / NCLI;
        int j = idx - i * NCLI;
        int a = i < j ? i : j;
        int b = i < j ? j : i;
        float c = G[a * NCLI + b] / (nrm[i] * nrm[j]);
        if (i == j) c -= 1.0f;
        cs[i][j] = c;
    }
    __syncthreads();

    if (t < NCLI) {
        float m = -1e30f;
        for (int j = 0; j < NCLI; ++j) m = fmaxf(m, cs[t][j]);
        maxcs[t] = m;
    }
    __syncthreads();

    if (t < NCLI) {
        float mi = maxcs[t];
        float m = -1e30f;
        for (int j = 0; j < NCLI; ++j) {
            float v = cs[t][j];
            float mj = maxcs[j];
            if (t != j && mi < mj) v *= mi / mj;  // pardoning
            m = fmaxf(m, v);
        }
        float x = 1.0f - m;
        x = fminf(fmaxf(x, 0.0f), 1.0f);
        wv[t] = x;
    }
    __syncthreads();

    if (t == 0) {
        float m = 0.0f;
        for (int i = 0; i < NCLI; ++i) m = fmaxf(m, wv[i]);
        red[0] = m;
    }
    __syncthreads();

    if (t < NCLI) {
        float x = wv[t] / red[0];
        if (x == 1.0f) x = 0.99f;
        float l = logf(x / (1.0f - x)) + 0.5f;
        float flag = isinf(l) ? 1.0f : 0.0f;   // torch: wv[isinf(wv)+wv > 1] = 1
        l = (flag + l > 1.0f) ? 1.0f : l;
        l = (l < 0.0f) ? 0.0f : l;
        wv[t] = l;
    }
    __syncthreads();

    if (t == 0) {
        float s = 0.0f;
        for (int i = 0; i < NCLI; ++i) s += wv[i];
        red[1] = s;
    }
    __syncthreads();

    if (t < NCLI) w[t] = wv[t] / red[1];
}

// ---------------- Output kernel: out[j] = dot(A[j][:], w), quarter-row ----------------
// 4 lanes per row (q = (lane&3) + 4k): wave touches 16 rows x 64B contiguous
// segments per instruction -> small L1 window, no thrash (r10: -40us).
// Tail-first block->row mapping preserves gram's L3 tail residency.
__global__ __launch_bounds__(256) void out_kernel(const float* __restrict__ A,
                                                  const float* __restrict__ w,
                                                  float* __restrict__ out, int d,
                                                  int nblocks) {
    __shared__ float4 w4s[NCLI / 4];
    if (threadIdx.x < NCLI / 4) w4s[threadIdx.x] = ((const float4*)w)[threadIdx.x];
    __syncthreads();

    const int lane = threadIdx.x & 63;
    const int wid = threadIdx.x >> 6;
    const int q0 = lane & 3;                  // quarter id 0..3
    const int rsub = lane >> 2;               // row-within-wave 0..15

    const long rb = (long)(nblocks - 1 - blockIdx.x) * 64;   // 64 rows/block, tail-first
    const long row = rb + wid * 16 + rsub;
    if (row >= d) return;

    const float4* r4 = (const float4*)(A + row * NCLI);
    float s = 0.0f;
#pragma unroll
    for (int k = 0; k < 6; ++k) {             // q = q0 + 4k  (0..23)
        float4 v = r4[q0 + 4 * k];
        float4 ww = w4s[q0 + 4 * k];
        s += v.x * ww.x + v.y * ww.y + v.z * ww.z + v.w * ww.w;
    }
    if (q0 == 0) {                            // tail q = 24
        float4 v = r4[24];
        float4 ww = w4s[24];
        s += v.x * ww.x + v.y * ww.y + v.z * ww.z + v.w * ww.w;
    }
    // reduce across the 4-lane quarter group
    s += __shfl_xor(s, 1, 64);
    s += __shfl_xor(s, 2, 64);
    if (q0 == 0) out[row] = s;
}

extern "C" void kernel_launch(void* const* d_in, const int* in_sizes, int n_in,
                              void* d_out, int out_size, void* d_ws, size_t ws_size,
                              hipStream_t stream) {
    const float* A = (const float*)d_in[0];
    float* out = (float*)d_out;
    const int d = in_sizes[0] / NCLI;

    float* G = (float*)d_ws;           // 100*100 f32 (upper triangle used)
    float* w = G + NCLI * NCLI;        // 100 f32 weights

    const int n4 = (NCLI * NCLI) / 4;  // 2500 float4
    zero_kernel<<<(n4 + 255) / 256, 256, 0, stream>>>((float4*)G, n4);

    const int nchunks = (d + DK - 1) / DK;
    const int gblocks = nchunks < GBLK ? nchunks : GBLK;
    gram_mfma<<<gblocks, 256, 0, stream>>>(A, G, (long)d, nchunks);

    weights_kernel<<<1, 128, 0, stream>>>(G, w);

    const int oblocks = (d + 63) / 64;  // 64 rows per block
    out_kernel<<<oblocks, 256, 0, stream>>>(A, w, out, d, oblocks);
}

// Round 16
// 182.436 us; speedup vs baseline: 1.2209x; 1.2209x over previous
//
#include <hip/hip_runtime.h>
#include <math.h>

#define NCLI 100
#define CPAD 112                  // clients padded to 7*16
#define DK   64                   // d-rows per chunk
#define RAWB 25600                // raw fp32 buffer: 25 pages x 1024 B (exact)
#define BFB  (CPAD * DK * 2)      // 14336 B bf16 transposed buffer
#define GBLK 512                  // 2 blocks/CU x 256 CU
#define NCOP 8                    // G accumulation copies (atomic fan-in 512->64)
#define GSTRIDE 10112             // floats per copy (padded; 40448 B, 16B-aligned)

typedef short bf16x8 __attribute__((ext_vector_type(8)));  // 8 bf16 (4 VGPRs)
typedef float f32x4  __attribute__((ext_vector_type(4)));

// bf16 buffer byte offset for (client c, k-offset t). Row stride 128B = 8 x 16B
// slots; slot = (c&7) ^ ((c>>3)&7)  (r9/r10/r14-verified).
__device__ __forceinline__ int bf_byte(int c, int t) {
    int s = (c & 7) ^ ((c >> 3) & 7);
    return c * 128 + ((t * 2) ^ (s << 4));
}

// fp32 -> bf16 (RNE), bit pattern as ushort
__device__ __forceinline__ unsigned short f2bf(float x) {
    unsigned u = __float_as_uint(x);
    unsigned r = (u + 0x7fffu + ((u >> 16) & 1u)) >> 16;
    return (unsigned short)r;
}

// ---------------- tiny zero kernel (graph-safe clear of the 8 G copies) ----------------
__global__ void zero_kernel(float4* __restrict__ p, int n4) {
    int i = blockIdx.x * blockDim.x + threadIdx.x;
    if (i < n4) p[i] = make_float4(0.f, 0.f, 0.f, 0.f);
}

// ---------------- reduce the 8 G copies into the final G ----------------
__global__ __launch_bounds__(256) void reduce_g(const float* __restrict__ Gp,
                                                float* __restrict__ Gf) {
    int i = blockIdx.x * blockDim.x + threadIdx.x;
    if (i < NCLI * NCLI) {
        float s = 0.0f;
#pragma unroll
        for (int c = 0; c < NCOP; ++c) s += Gp[c * GSTRIDE + i];
        Gf[i] = s;
    }
}

// ---- async DMA, per-wave pages: chunk (64 rows x 400B, contiguous) -> raw ----
// 25 pages x 1024 B. Wave w copies pages 6w..6w+5; wave 0 also page 24.
// Per-wave issue counts: wave0=7, waves1-3=6 (vmcnt waits match per wave).
__device__ __forceinline__ void stage_issue(const float* __restrict__ A, long c0,
                                            char* raw, int tid, long dtot) {
    const int lane = tid & 63;
    const int w = tid >> 6;
    const long gword0 = c0 * (DK * NCLI);    // 6400 floats per chunk
    const long gmax = dtot * NCLI - 4;       // last safe float4 word start
#pragma unroll
    for (int p = 0; p < 6; ++p) {
        const int page = w * 6 + p;
        long gw = gword0 + page * 256 + lane * 4;
        if (gw > gmax) gw = gmax;
        __builtin_amdgcn_global_load_lds(
            (const __attribute__((address_space(1))) unsigned*)(A + gw),
            (__attribute__((address_space(3))) unsigned*)(raw + page * 1024),
            16, 0, 0);
    }
    if (w == 0) {
        long gw = gword0 + 24 * 256 + lane * 4;
        if (gw > gmax) gw = gmax;
        __builtin_amdgcn_global_load_lds(
            (const __attribute__((address_space(1))) unsigned*)(A + gw),
            (__attribute__((address_space(3))) unsigned*)(raw + 24 * 1024),
            16, 0, 0);
    }
}

// ---- LDS->LDS transpose + fp32->bf16 convert (raw linear -> bf swizzled) ----
__device__ __forceinline__ void transpose_convert(const char* raw, char* bf,
                                                  int tid, long d0, long dtot) {
#pragma unroll
    for (int s = 0; s < 2; ++s) {
        if (s == 0 || tid < 144) {
            const int u = tid + s * 256;
            const int rg = u / 25;           // 4-row group 0..15
            const int cg = u - rg * 25;      // 4-col group 0..24
            float4 v[4];
#pragma unroll
            for (int r = 0; r < 4; ++r) {
                v[r] = *(const float4*)(raw + (((rg * 4 + r) * 25 + cg) << 4));
                if (d0 + rg * 4 + r >= dtot) v[r] = make_float4(0.f, 0.f, 0.f, 0.f);
            }
#pragma unroll
            for (int j = 0; j < 4; ++j) {
                const int c = cg * 4 + j;
                ushort4 p;
                p.x = f2bf(((const float*)&v[0])[j]);
                p.y = f2bf(((const float*)&v[1])[j]);
                p.z = f2bf(((const float*)&v[2])[j]);
                p.w = f2bf(((const float*)&v[3])[j]);
                *(ushort4*)(bf + bf_byte(c, rg * 4)) = p;   // 8B, 8B-aligned
            }
        }
    }
}

// Wave W owns 16x16 output tiles: row a=W, b=W..6 (7-W tiles) and, for W>0,
// row a=7-W, b=7-W..6 (W tiles). Exactly 7 tiles per wave, A-frags {W, 7-W}.
template <int W>
__device__ __forceinline__ void compute_chunk(const char* bf, f32x4 acc[7]) {
    const int lane = threadIdx.x & 63;
    const int lrow = lane & 15;        // row/col within tile
    const int kgrp = lane >> 4;        // k-group 0..3 (8 bf16 each)
    constexpr int NB = 7 - W;          // b = W..6
#pragma unroll
    for (int kk = 0; kk < DK; kk += 32) {
        const int kb = kk + kgrp * 8;
        bf16x8 bfr[NB];
#pragma unroll
        for (int j = 0; j < NB; ++j)
            bfr[j] = *(const bf16x8*)(bf + bf_byte((W + j) * 16 + lrow, kb));
        bf16x8 a0 = *(const bf16x8*)(bf + bf_byte(W * 16 + lrow, kb));
#pragma unroll
        for (int j = 0; j < NB; ++j)
            acc[j] = __builtin_amdgcn_mfma_f32_16x16x32_bf16(a0, bfr[j], acc[j], 0, 0, 0);
        if constexpr (W > 0) {
            bf16x8 a1 = *(const bf16x8*)(bf + bf_byte((7 - W) * 16 + lrow, kb));
#pragma unroll
            for (int j = 0; j < W; ++j)
                acc[NB + j] = __builtin_amdgcn_mfma_f32_16x16x32_bf16(
                    a1, bfr[NB - W + j], acc[NB + j], 0, 0, 0);
        }
    }
}

template <int W>
__device__ __forceinline__ void store_acc(float* __restrict__ G, const f32x4 acc[7]) {
    const int lane = threadIdx.x & 63;
    const int cn = lane & 15;                 // output col within tile
    const int r0 = (lane >> 4) * 4;           // output row base within tile
#pragma unroll
    for (int j = 0; j < 7 - W; ++j) {         // tiles (W, W+j)
#pragma unroll
        for (int r = 0; r < 4; ++r) {
            int i = W * 16 + r0 + r;
            int k = (W + j) * 16 + cn;
            if (i < NCLI && k < NCLI) atomicAdd(&G[i * NCLI + k], acc[j][r]);
        }
    }
    if constexpr (W > 0) {
#pragma unroll
        for (int j = 0; j < W; ++j) {         // tiles (7-W, 7-W+j)
#pragma unroll
            for (int r = 0; r < 4; ++r) {
                int i = (7 - W) * 16 + r0 + r;
                int k = (7 - W + j) * 16 + cn;
                if (i < NCLI && k < NCLI) atomicAdd(&G[i * NCLI + k], acc[7 - W + j][r]);
            }
        }
    }
}

// ---------------- MFMA Gram: r14 loop + 8-way split atomic target ----------------
// Loop identical to r14 (best, 199us). Only change: block b accumulates into
// G copy b&7 -> per-address atomic fan-in 512 -> 64, shrinking the end-of-kernel
// atomic storm (512 co-resident blocks finishing together, 2.6M atomics onto
// 40KB; estimated 15-25us serialized tail).
__global__ __launch_bounds__(256, 2) void gram_mfma(const float* __restrict__ A,
                                                    float* __restrict__ Gp,
                                                    long dtot, int nchunks) {
    __shared__ uint4 ldsq[(2 * RAWB + 2 * BFB) / 16];   // 79872 B -> 2 blocks/CU
    char* lds = (char*)ldsq;
    char* bf = lds + 2 * RAWB;
    const int tid = threadIdx.x;
    const int wid = tid >> 6;

    // zero pad-client rows 100..111 in BOTH bf buffers (whole rows zero)
    for (int u = tid; u < 2 * (CPAD - NCLI) * 32; u += 256) {
        int b = u / ((CPAD - NCLI) * 32);
        int o = u - b * ((CPAD - NCLI) * 32);
        ((unsigned*)(bf + b * BFB + NCLI * 128))[o] = 0u;
    }
    __syncthreads();

    f32x4 acc[7];
#pragma unroll
    for (int q = 0; q < 7; ++q) acc[q] = (f32x4)(0.0f);

    int nb = 0;
    if ((int)blockIdx.x < nchunks)
        nb = (nchunks - 1 - (int)blockIdx.x) / (int)gridDim.x + 1;

    if (nb > 0)
        stage_issue(A, (long)blockIdx.x, lds, tid, dtot);   // prologue -> raw0

    for (int e = 0; e < nb; ++e) {
        if (e + 1 < nb) {
            stage_issue(A, (long)blockIdx.x + (long)(e + 1) * gridDim.x,
                        lds + ((e + 1) & 1) * RAWB, tid, dtot);
            // drain chunk e only; chunk e+1 (7/6 issues per wave) stays in flight
            if (wid == 0) asm volatile("s_waitcnt vmcnt(7)" ::: "memory");
            else          asm volatile("s_waitcnt vmcnt(6)" ::: "memory");
        } else {
            asm volatile("s_waitcnt vmcnt(0)" ::: "memory");
        }
        __builtin_amdgcn_s_barrier();
        asm volatile("" ::: "memory");

        // merged phase: compute previous chunk || transpose current chunk
        if (e > 0) {
            const char* bfp = bf + ((e - 1) & 1) * BFB;
            if (wid == 0)      compute_chunk<0>(bfp, acc);
            else if (wid == 1) compute_chunk<1>(bfp, acc);
            else if (wid == 2) compute_chunk<2>(bfp, acc);
            else               compute_chunk<3>(bfp, acc);
        }
        transpose_convert(lds + (e & 1) * RAWB, bf + (e & 1) * BFB, tid,
                          ((long)blockIdx.x + (long)e * gridDim.x) * DK, dtot);

        asm volatile("s_waitcnt lgkmcnt(0)" ::: "memory");
        __builtin_amdgcn_s_barrier();
        asm volatile("" ::: "memory");
    }

    // epilogue: compute the last chunk
    if (nb > 0) {
        const char* bfp = bf + ((nb - 1) & 1) * BFB;
        if (wid == 0)      compute_chunk<0>(bfp, acc);
        else if (wid == 1) compute_chunk<1>(bfp, acc);
        else if (wid == 2) compute_chunk<2>(bfp, acc);
        else               compute_chunk<3>(bfp, acc);
    }

    float* Gc = Gp + (blockIdx.x & (NCOP - 1)) * GSTRIDE;
    if (wid == 0)      store_acc<0>(Gc, acc);
    else if (wid == 1) store_acc<1>(Gc, acc);
    else if (wid == 2) store_acc<2>(Gc, acc);
    else               store_acc<3>(Gc, acc);
}

// ---------------- Weights kernel: full FoolsGold weight computation, single block ----------------
__global__ __launch_bounds__(128) void weights_kernel(const float* __restrict__ G,
                                                      float* __restrict__ w) {
    __shared__ float cs[NCLI][NCLI + 1];
    __shared__ float nrm[NCLI], maxcs[NCLI], wv[NCLI];
    __shared__ float red[2];
    const int t = threadIdx.x;

    if (t < NCLI) {
        float g = G[t * NCLI + t];
        nrm[t] = fmaxf(sqrtf(g), 1e-12f);
    }
    __syncthreads();

    for (int idx = t; idx < NCLI * NCLI; idx += 128) {
        int i = idx / NCLI;
        int j = idx - i * NCLI;
        int a = i < j ? i : j;
        int b = i < j ? j : i;
        float c = G[a * NCLI + b] / (nrm[i] * nrm[j]);
        if (i == j) c -= 1.0f;
        cs[i][j] = c;
    }
    __syncthreads();

    if (t < NCLI) {
        float m = -1e30f;
        for (int j = 0; j < NCLI; ++j) m = fmaxf(m, cs[t][j]);
        maxcs[t] = m;
    }
    __syncthreads();

    if (t < NCLI) {
        float mi = maxcs[t];
        float m = -1e30f;
        for (int j = 0; j < NCLI; ++j) {
            float v = cs[t][j];
            float mj = maxcs[j];
            if (t != j && mi < mj) v *= mi / mj;  // pardoning
            m = fmaxf(m, v);
        }
        float x = 1.0f - m;
        x = fminf(fmaxf(x, 0.0f), 1.0f);
        wv[t] = x;
    }
    __syncthreads();

    if (t == 0) {
        float m = 0.0f;
        for (int i = 0; i < NCLI; ++i) m = fmaxf(m, wv[i]);
        red[0] = m;
    }
    __syncthreads();

    if (t < NCLI) {
        float x = wv[t] / red[0];
        if (x == 1.0f) x = 0.99f;
        float l = logf(x / (1.0f - x)) + 0.5f;
        float flag = isinf(l) ? 1.0f : 0.0f;   // torch: wv[isinf(wv)+wv > 1] = 1
        l = (flag + l > 1.0f) ? 1.0f : l;
        l = (l < 0.0f) ? 0.0f : l;
        wv[t] = l;
    }
    __syncthreads();

    if (t == 0) {
        float s = 0.0f;
        for (int i = 0; i < NCLI; ++i) s += wv[i];
        red[1] = s;
    }
    __syncthreads();

    if (t < NCLI) w[t] = wv[t] / red[1];
}

// ---------------- Output kernel: out[j] = dot(A[j][:], w), quarter-row ----------------
__global__ __launch_bounds__(256) void out_kernel(const float* __restrict__ A,
                                                  const float* __restrict__ w,
                                                  float* __restrict__ out, int d,
                                                  int nblocks) {
    __shared__ float4 w4s[NCLI / 4];
    if (threadIdx.x < NCLI / 4) w4s[threadIdx.x] = ((const float4*)w)[threadIdx.x];
    __syncthreads();

    const int lane = threadIdx.x & 63;
    const int wid = threadIdx.x >> 6;
    const int q0 = lane & 3;                  // quarter id 0..3
    const int rsub = lane >> 2;               // row-within-wave 0..15

    const long rb = (long)(nblocks - 1 - blockIdx.x) * 64;   // tail-first
    const long row = rb + wid * 16 + rsub;
    if (row >= d) return;

    const float4* r4 = (const float4*)(A + row * NCLI);
    float s = 0.0f;
#pragma unroll
    for (int k = 0; k < 6; ++k) {             // q = q0 + 4k  (0..23)
        float4 v = r4[q0 + 4 * k];
        float4 ww = w4s[q0 + 4 * k];
        s += v.x * ww.x + v.y * ww.y + v.z * ww.z + v.w * ww.w;
    }
    if (q0 == 0) {                            // tail q = 24
        float4 v = r4[24];
        float4 ww = w4s[24];
        s += v.x * ww.x + v.y * ww.y + v.z * ww.z + v.w * ww.w;
    }
    s += __shfl_xor(s, 1, 64);
    s += __shfl_xor(s, 2, 64);
    if (q0 == 0) out[row] = s;
}

extern "C" void kernel_launch(void* const* d_in, const int* in_sizes, int n_in,
                              void* d_out, int out_size, void* d_ws, size_t ws_size,
                              hipStream_t stream) {
    const float* A = (const float*)d_in[0];
    float* out = (float*)d_out;
    const int d = in_sizes[0] / NCLI;

    float* Gp = (float*)d_ws;                    // 8 copies, stride GSTRIDE
    float* Gf = Gp + NCOP * GSTRIDE;             // final G (100x100)
    float* w = Gf + NCLI * NCLI;                 // 100 weights

    const int n4 = (NCOP * GSTRIDE) / 4;         // 20224 float4
    zero_kernel<<<(n4 + 255) / 256, 256, 0, stream>>>((float4*)Gp, n4);

    const int nchunks = (d + DK - 1) / DK;
    const int gblocks = nchunks < GBLK ? nchunks : GBLK;
    gram_mfma<<<gblocks, 256, 0, stream>>>(A, Gp, (long)d, nchunks);

    reduce_g<<<(NCLI * NCLI + 255) / 256, 256, 0, stream>>>(Gp, Gf);

    weights_kernel<<<1, 128, 0, stream>>>(Gf, w);

    const int oblocks = (d + 63) / 64;  // 64 rows per block
    out_kernel<<<oblocks, 256, 0, stream>>>(A, w, out, d, oblocks);
}